// Round 1
// baseline (892.118 us; speedup 1.0000x reference)
//
#include <hip/hip_runtime.h>
#include <hip/hip_bf16.h>
#include <math.h>

#define DM 768
#define ED 1536
#define NS 16
#define DTR 48
#define BATCH 16
#define LQ 197
#define NTOK (BATCH*LQ)      // 3152
#define NWTOK (64*49)        // 3136

typedef __attribute__((ext_vector_type(8))) short short8;
typedef __attribute__((ext_vector_type(4))) float f32x4;

__device__ __forceinline__ unsigned short f2bf(float f) {
  unsigned int u = __float_as_uint(f);
  unsigned int r = (u + 0x7FFFu + ((u >> 16) & 1u)) >> 16;
  return (unsigned short)r;
}
__device__ __forceinline__ float silu_f(float x) {
  return x / (1.f + __expf(-x));
}

// ---------------- f32 -> bf16 convert ----------------
__global__ void k_f2bf(const float* __restrict__ in, unsigned short* __restrict__ out, int n) {
  int i = blockIdx.x * 256 + threadIdx.x;
  if (i < n) out[i] = f2bf(in[i]);
}

// ---------------- bf16 MFMA GEMM: C[M][N] = A[M][K] * B[N][K]^T ----------------
// mode 0: plain fp32 store (ldc = N)
// mode 1: split epilogue for xz: cols < ED -> C (xin), cols >= ED -> C2 = silu (z)
__global__ __launch_bounds__(256) void k_gemm(
    const unsigned short* __restrict__ A, const unsigned short* __restrict__ B,
    float* __restrict__ C, float* __restrict__ C2,
    int M, int N, int K, int mode)
{
  int wave = threadIdx.x >> 6;
  int lane = threadIdx.x & 63;
  int m0 = blockIdx.x * 128 + (wave >> 1) * 64;
  int n0 = blockIdx.y * 128 + (wave & 1) * 64;
  int lr = lane & 15;
  int kof0 = (lane >> 4) * 8;

  f32x4 acc[4][4];
#pragma unroll
  for (int i = 0; i < 4; ++i)
#pragma unroll
    for (int j = 0; j < 4; ++j) acc[i][j] = (f32x4){0.f, 0.f, 0.f, 0.f};

  const unsigned short* Ap[4];
  const unsigned short* Bp[4];
#pragma unroll
  for (int i = 0; i < 4; ++i) {
    int r = m0 + i * 16 + lr; if (r > M - 1) r = M - 1;
    Ap[i] = A + (size_t)r * K + kof0;
  }
#pragma unroll
  for (int j = 0; j < 4; ++j) {
    int r = n0 + j * 16 + lr; if (r > N - 1) r = N - 1;
    Bp[j] = B + (size_t)r * K + kof0;
  }

  for (int kk = 0; kk < K; kk += 32) {
    short8 av[4], bv[4];
#pragma unroll
    for (int i = 0; i < 4; ++i) av[i] = *(const short8*)(Ap[i] + kk);
#pragma unroll
    for (int j = 0; j < 4; ++j) bv[j] = *(const short8*)(Bp[j] + kk);
#pragma unroll
    for (int i = 0; i < 4; ++i)
#pragma unroll
      for (int j = 0; j < 4; ++j)
        acc[i][j] = __builtin_amdgcn_mfma_f32_16x16x32_bf16(av[i], bv[j], acc[i][j], 0, 0, 0);
  }

  int cn = lane & 15;
  int rb = (lane >> 4) * 4;
#pragma unroll
  for (int i = 0; i < 4; ++i)
#pragma unroll
    for (int j = 0; j < 4; ++j)
#pragma unroll
      for (int r = 0; r < 4; ++r) {
        int row = m0 + i * 16 + rb + r;
        int col = n0 + j * 16 + cn;
        if (row < M && col < N) {
          float v = acc[i][j][r];
          if (mode == 1) {
            if (col < ED) C[(size_t)row * ED + col] = v;
            else          C2[(size_t)row * ED + (col - ED)] = silu_f(v);
          } else {
            C[(size_t)row * N + col] = v;
          }
        }
      }
}

// ---------------- causal depthwise conv (k=4) + bias + silu ----------------
// perm 0: identity sequence; perm 1: 14x14 transpose sequence (class token last)
__global__ __launch_bounds__(256) void k_conv(
    const float* __restrict__ xin, const float* __restrict__ cw,
    const float* __restrict__ cb, float* __restrict__ u,
    unsigned short* __restrict__ ub, int perm)
{
  int t = blockIdx.x;   // 0..196
  int b = blockIdx.y;   // 0..15
  int src[4];
#pragma unroll
  for (int k = 0; k < 4; ++k) {
    int tt = t - 3 + k;
    if (tt < 0) src[k] = -1;
    else if (perm == 0) src[k] = tt;
    else src[k] = (tt < 196) ? ((tt % 14) * 14 + tt / 14) : 196;
  }
  int obase = (b * LQ + t) * ED;
  for (int e = threadIdx.x; e < ED; e += 256) {
    float s = cb[e];
#pragma unroll
    for (int k = 0; k < 4; ++k)
      if (src[k] >= 0) s += xin[(b * LQ + src[k]) * ED + e] * cw[e * 4 + k];
    float v = silu_f(s);
    u[obase + e] = v;
    ub[obase + e] = f2bf(v);
  }
}

// ---------------- window (1x1 conv) scale + bias + silu ----------------
__global__ __launch_bounds__(256) void k_win(
    const float* __restrict__ xin, const float* __restrict__ w2,
    const float* __restrict__ b2, float* __restrict__ u,
    unsigned short* __restrict__ ub)
{
  int j = blockIdx.x;  // 0..48
  int s = blockIdx.y;  // 0..63
  int q = s >> 4, b = s & 15;
  int hh = j / 7 + 7 * (q >> 1);
  int ww = j % 7 + 7 * (q & 1);
  int tok = hh * 14 + ww;
  int ibase = (b * LQ + tok) * ED;
  int obase = (s * 49 + j) * ED;
  for (int e = threadIdx.x; e < ED; e += 256) {
    float v = silu_f(xin[ibase + e] * w2[e] + b2[e]);
    u[obase + e] = v;
    ub[obase + e] = f2bf(v);
  }
}

// ---------------- delta = softplus(dbc[:, :48] @ dt_w^T + dt_b) ----------------
// grid: (6, ntok/16); each thread owns one e (dt_w row in regs), 16 tokens per block
__global__ __launch_bounds__(256) void k_delta(
    const float* __restrict__ dbc, const float* __restrict__ dtw,
    const float* __restrict__ dtb, float* __restrict__ delta)
{
  __shared__ float sd[16][DTR];
  int tbase = blockIdx.y * 16;
  int e = blockIdx.x * 256 + threadIdx.x;
  for (int i = threadIdx.x; i < 16 * DTR; i += 256)
    sd[i / DTR][i % DTR] = dbc[(tbase + i / DTR) * 80 + (i % DTR)];
  __syncthreads();
  float w[DTR];
#pragma unroll
  for (int k = 0; k < DTR; ++k) w[k] = dtw[e * DTR + k];
  float bias = dtb[e];
  for (int tt = 0; tt < 16; ++tt) {
    float s = bias;
#pragma unroll
    for (int k = 0; k < DTR; ++k) s += sd[tt][k] * w[k];
    float dv = (s > 20.f) ? s : log1pf(__expf(s));
    delta[(size_t)(tbase + tt) * ED + e] = dv;
  }
}

// ---------------- SSM scan + scatter-accumulate ----------------
// 16 lanes = 16 states per (seq, e) group; lane n==0 writes.
// mode 0: branch0  (seq=b, L=197, dest pos = (t+1)%197)
// mode 1: branch1  (dest pos = perm(t)+1 for t<196 else 0; also writes ct1 at t==196)
// mode 2: windows  (seq = q*16+b, L=49, dest pos = window token)
__global__ __launch_bounds__(256) void k_scan(
    const float* __restrict__ u, const float* __restrict__ delta,
    const float* __restrict__ dbc, const float* __restrict__ alog,
    float* __restrict__ acc, float* __restrict__ ct1,
    int mode, int Ls)
{
  int g = blockIdx.x * 16 + (threadIdx.x >> 4);
  int n = threadIdx.x & 15;
  int e = g % ED;
  int seq = g / ED;
  float A = -__expf(alog[e * NS + n]);
  float h = 0.f;
  int bq = seq & 15, q = seq >> 4;  // mode 2 decode
  for (int t = 0; t < Ls; ++t) {
    int ti = seq * Ls + t;
    float d  = delta[(size_t)ti * ED + e];
    float uv = u[(size_t)ti * ED + e];
    float Bv = dbc[ti * 80 + DTR + n];
    float Cv = dbc[ti * 80 + DTR + NS + n];
    h = __expf(d * A) * h + (d * uv) * Bv;
    float y = Cv * h;
    y += __shfl_xor(y, 8);
    y += __shfl_xor(y, 4);
    y += __shfl_xor(y, 2);
    y += __shfl_xor(y, 1);
    if (n == 0) {
      int pos, bb;
      if (mode == 0)      { bb = seq; pos = (t + 1) % LQ; }
      else if (mode == 1) { bb = seq; pos = (t < 196) ? ((t % 14) * 14 + t / 14 + 1) : 0; }
      else {
        bb = bq;
        int hh = t / 7 + 7 * (q >> 1);
        int ww = t % 7 + 7 * (q & 1);
        pos = hh * 14 + ww;
      }
      acc[(size_t)(bb * LQ + pos) * ED + e] += y;
      if (mode == 1 && t == 196) ct1[seq * ED + e] = y;
    }
  }
}

// ---------------- add ct1 (branch-1 class-token y) at position 196 ----------------
__global__ void k_ct1(const float* __restrict__ ct1, float* __restrict__ acc) {
  int i = blockIdx.x * 256 + threadIdx.x;
  if (i < BATCH * ED) {
    int b = i / ED, e = i % ED;
    acc[(size_t)(b * LQ + 196) * ED + e] += ct1[i];
  }
}

// ---------------- pre-out = acc * silu(z), to bf16 ----------------
__global__ void k_mulz(const float* __restrict__ acc, const float* __restrict__ zs,
                       unsigned short* __restrict__ preb, int n) {
  int i = blockIdx.x * 256 + threadIdx.x;
  if (i < n) preb[i] = f2bf(acc[i] * zs[i]);
}

extern "C" void kernel_launch(void* const* d_in, const int* in_sizes, int n_in,
                              void* d_out, int out_size, void* d_ws, size_t ws_size,
                              hipStream_t stream)
{
  const float* x    = (const float*)d_in[0];
  const float* Win  = (const float*)d_in[1];
  const float* c0w  = (const float*)d_in[2];
  const float* c0b  = (const float*)d_in[3];
  const float* c1w  = (const float*)d_in[4];
  const float* c1b  = (const float*)d_in[5];
  const float* c2w  = (const float*)d_in[6];
  const float* c2b  = (const float*)d_in[7];
  const float* xp0  = (const float*)d_in[8];
  const float* xp1  = (const float*)d_in[9];
  const float* xp2  = (const float*)d_in[10];
  const float* dtw  = (const float*)d_in[11];
  const float* dtb  = (const float*)d_in[12];
  const float* alog = (const float*)d_in[13];
  const float* Wout = (const float*)d_in[15];
  float* out = (float*)d_out;

  char* base = (char*)d_ws;
  size_t off = 0;
  auto alloc = [&](size_t bytes) -> char* {
    char* r = base + off;
    off = (off + bytes + 255) & ~(size_t)255;
    return r;
  };

  float* XIN   = (float*)alloc((size_t)NTOK * ED * 4);
  float* ZS    = (float*)alloc((size_t)NTOK * ED * 4);
  float* ACC   = (float*)alloc((size_t)NTOK * ED * 4);
  float* U     = (float*)alloc((size_t)NTOK * ED * 4);
  float* DELTA = (float*)alloc((size_t)NTOK * ED * 4);
  float* DBC   = (float*)alloc((size_t)NTOK * 80 * 4);
  float* CT1   = (float*)alloc((size_t)BATCH * ED * 4);
  unsigned short* XB    = (unsigned short*)alloc((size_t)NTOK * DM * 2);
  unsigned short* WINB  = (unsigned short*)alloc((size_t)2 * ED * DM * 2);
  unsigned short* XPB0  = (unsigned short*)alloc((size_t)80 * ED * 2);
  unsigned short* XPB1  = (unsigned short*)alloc((size_t)80 * ED * 2);
  unsigned short* XPB2  = (unsigned short*)alloc((size_t)80 * ED * 2);
  unsigned short* WOUTB = (unsigned short*)alloc((size_t)DM * ED * 2);
  unsigned short* UB    = (unsigned short*)alloc((size_t)NTOK * ED * 2);
  unsigned short* PREB  = (unsigned short*)alloc((size_t)NTOK * ED * 2);

  auto cvt = [&](const float* s, unsigned short* d, int n) {
    k_f2bf<<<(n + 255) / 256, 256, 0, stream>>>(s, d, n);
  };
  cvt(x, XB, NTOK * DM);
  cvt(Win, WINB, 2 * ED * DM);
  cvt(xp0, XPB0, 80 * ED);
  cvt(xp1, XPB1, 80 * ED);
  cvt(xp2, XPB2, 80 * ED);
  cvt(Wout, WOUTB, DM * ED);

  // xz = x @ W_in^T  -> XIN (first ED cols), ZS = silu(z)
  k_gemm<<<dim3(25, 24), 256, 0, stream>>>(XB, WINB, XIN, ZS, NTOK, 2 * ED, DM, 1);
  hipMemsetAsync(ACC, 0, (size_t)NTOK * ED * 4, stream);

  // ---- branch 0 (row-major sequence) ----
  k_conv<<<dim3(197, 16), 256, 0, stream>>>(XIN, c0w, c0b, U, UB, 0);
  k_gemm<<<dim3(25, 1), 256, 0, stream>>>(UB, XPB0, DBC, nullptr, NTOK, 80, ED, 0);
  k_delta<<<dim3(6, NTOK / 16), 256, 0, stream>>>(DBC, dtw, dtb, DELTA);
  k_scan<<<16 * 96, 256, 0, stream>>>(U, DELTA, DBC, alog, ACC, CT1, 0, LQ);

  // ---- branch 1 (transposed spatial sequence) ----
  k_conv<<<dim3(197, 16), 256, 0, stream>>>(XIN, c1w, c1b, U, UB, 1);
  k_gemm<<<dim3(25, 1), 256, 0, stream>>>(UB, XPB1, DBC, nullptr, NTOK, 80, ED, 0);
  k_delta<<<dim3(6, NTOK / 16), 256, 0, stream>>>(DBC, dtw, dtb, DELTA);
  k_scan<<<16 * 96, 256, 0, stream>>>(U, DELTA, DBC, alog, ACC, CT1, 1, LQ);

  // ---- branch 2 (four 7x7 windows) ----
  k_win<<<dim3(49, 64), 256, 0, stream>>>(XIN, c2w, c2b, U, UB);
  k_gemm<<<dim3(25, 1), 256, 0, stream>>>(UB, XPB2, DBC, nullptr, NWTOK, 80, ED, 0);
  k_delta<<<dim3(6, NWTOK / 16), 256, 0, stream>>>(DBC, dtw, dtb, DELTA);
  k_scan<<<64 * 96, 256, 0, stream>>>(U, DELTA, DBC, alog, ACC, CT1, 2, 49);

  k_ct1<<<(BATCH * ED + 255) / 256, 256, 0, stream>>>(CT1, ACC);
  k_mulz<<<(NTOK * ED + 255) / 256, 256, 0, stream>>>(ACC, ZS, PREB, NTOK * ED);

  // out = (acc * silu(z)) @ W_out^T
  k_gemm<<<dim3(25, 6), 256, 0, stream>>>(PREB, WOUTB, out, nullptr, NTOK, DM, ED, 0);
}

// Round 2
// 629.311 us; speedup vs baseline: 1.4176x; 1.4176x over previous
//
#include <hip/hip_runtime.h>
#include <hip/hip_bf16.h>
#include <math.h>

#define DM 768
#define ED 1536
#define NS 16
#define DTR 48
#define BATCH 16
#define LQ 197
#define NTOK (BATCH*LQ)      // 3152
#define NWTOK (64*49)        // 3136

typedef __attribute__((ext_vector_type(8))) short short8;
typedef __attribute__((ext_vector_type(4))) float f32x4;
typedef __attribute__((ext_vector_type(4))) short s16x4;

__device__ __forceinline__ unsigned short f2bf(float f) {
  unsigned int u = __float_as_uint(f);
  unsigned int r = (u + 0x7FFFu + ((u >> 16) & 1u)) >> 16;
  return (unsigned short)r;
}
__device__ __forceinline__ float silu_f(float x) {
  return x / (1.f + __expf(-x));
}

// ---------------- f32 -> bf16 convert ----------------
__global__ void k_f2bf(const float* __restrict__ in, unsigned short* __restrict__ out, int n) {
  int i = blockIdx.x * 256 + threadIdx.x;
  if (i < n) out[i] = f2bf(in[i]);
}

// ---------------- bf16 MFMA GEMM: C[M][N] = A[M][K] * B[N][K]^T ----------------
// mode 0: plain fp32 store (ldc = N)
// mode 1: split epilogue for xz: cols < ED -> C (xin), cols >= ED -> C2 = silu (z)
__global__ __launch_bounds__(256) void k_gemm(
    const unsigned short* __restrict__ A, const unsigned short* __restrict__ B,
    float* __restrict__ C, float* __restrict__ C2,
    int M, int N, int K, int mode)
{
  int wave = threadIdx.x >> 6;
  int lane = threadIdx.x & 63;
  int m0 = blockIdx.x * 128 + (wave >> 1) * 64;
  int n0 = blockIdx.y * 128 + (wave & 1) * 64;
  int lr = lane & 15;
  int kof0 = (lane >> 4) * 8;

  f32x4 acc[4][4];
#pragma unroll
  for (int i = 0; i < 4; ++i)
#pragma unroll
    for (int j = 0; j < 4; ++j) acc[i][j] = (f32x4){0.f, 0.f, 0.f, 0.f};

  const unsigned short* Ap[4];
  const unsigned short* Bp[4];
#pragma unroll
  for (int i = 0; i < 4; ++i) {
    int r = m0 + i * 16 + lr; if (r > M - 1) r = M - 1;
    Ap[i] = A + (size_t)r * K + kof0;
  }
#pragma unroll
  for (int j = 0; j < 4; ++j) {
    int r = n0 + j * 16 + lr; if (r > N - 1) r = N - 1;
    Bp[j] = B + (size_t)r * K + kof0;
  }

  for (int kk = 0; kk < K; kk += 32) {
    short8 av[4], bv[4];
#pragma unroll
    for (int i = 0; i < 4; ++i) av[i] = *(const short8*)(Ap[i] + kk);
#pragma unroll
    for (int j = 0; j < 4; ++j) bv[j] = *(const short8*)(Bp[j] + kk);
#pragma unroll
    for (int i = 0; i < 4; ++i)
#pragma unroll
      for (int j = 0; j < 4; ++j)
        acc[i][j] = __builtin_amdgcn_mfma_f32_16x16x32_bf16(av[i], bv[j], acc[i][j], 0, 0, 0);
  }

  int cn = lane & 15;
  int rb = (lane >> 4) * 4;
#pragma unroll
  for (int i = 0; i < 4; ++i)
#pragma unroll
    for (int j = 0; j < 4; ++j)
#pragma unroll
      for (int r = 0; r < 4; ++r) {
        int row = m0 + i * 16 + rb + r;
        int col = n0 + j * 16 + cn;
        if (row < M && col < N) {
          float v = acc[i][j][r];
          if (mode == 1) {
            if (col < ED) C[(size_t)row * ED + col] = v;
            else          C2[(size_t)row * ED + (col - ED)] = silu_f(v);
          } else {
            C[(size_t)row * N + col] = v;
          }
        }
      }
}

// ---------------- small GEMM for dbc: C[M][80] += A[M][1536] * B[80][1536]^T ----------------
// one wave per (16-row m-tile, k-split); fp32 atomicAdd epilogue; C pre-zeroed.
__global__ __launch_bounds__(256) void k_dbc(
    const unsigned short* __restrict__ A, const unsigned short* __restrict__ B,
    float* __restrict__ C, int M)
{
  const int KSPLIT = 16, KSPAN = ED / KSPLIT;  // 96 -> 3 k-steps
  int wid = blockIdx.x * 4 + (threadIdx.x >> 6);
  int lane = threadIdx.x & 63;
  int mt = wid / KSPLIT, ks = wid % KSPLIT;
  int m0 = mt * 16;
  if (m0 >= M) return;
  int lr = lane & 15;
  int kof = ks * KSPAN + (lane >> 4) * 8;

  f32x4 acc[5];
#pragma unroll
  for (int j = 0; j < 5; ++j) acc[j] = (f32x4){0.f, 0.f, 0.f, 0.f};

  const unsigned short* Ap = A + (size_t)(m0 + lr) * ED + kof;
  const unsigned short* Bp = B + (size_t)lr * ED + kof;
#pragma unroll
  for (int kk = 0; kk < KSPAN; kk += 32) {
    short8 av = *(const short8*)(Ap + kk);
#pragma unroll
    for (int j = 0; j < 5; ++j) {
      short8 bv = *(const short8*)(Bp + (size_t)j * 16 * ED + kk);
      acc[j] = __builtin_amdgcn_mfma_f32_16x16x32_bf16(av, bv, acc[j], 0, 0, 0);
    }
  }
  int cn = lane & 15, rb = (lane >> 4) * 4;
#pragma unroll
  for (int j = 0; j < 5; ++j)
#pragma unroll
    for (int r = 0; r < 4; ++r)
      atomicAdd(&C[(size_t)(m0 + rb + r) * 80 + j * 16 + cn], acc[j][r]);
}

// ---------------- causal depthwise conv (k=4) + bias + silu -> UT (fp32, [e][b*Lp+t]) + UB (bf16, [tok][e]) ----------------
__global__ __launch_bounds__(256) void k_conv(
    const float* __restrict__ xin, const float* __restrict__ cw,
    const float* __restrict__ cb, float* __restrict__ UT,
    unsigned short* __restrict__ UB, int perm, int Lp, int SLp)
{
  __shared__ float xs[LQ][17];
  __shared__ float us[LQ][17];
  int eb = blockIdx.x;      // 0..95
  int b  = blockIdx.y;      // 0..15
  int e0 = eb * 16;
  for (int i = threadIdx.x; i < LQ * 16; i += 256) {
    int tt = i >> 4, le = i & 15;
    int tok = (perm == 0) ? tt : (tt < 196 ? (tt % 14) * 14 + tt / 14 : 196);
    xs[tt][le] = xin[((size_t)(b * LQ + tok)) * ED + e0 + le];
  }
  __syncthreads();
  {
    int le = threadIdx.x & 15, tq = threadIdx.x >> 4;
    int e = e0 + le;
    float w0 = cw[e * 4], w1 = cw[e * 4 + 1], w2 = cw[e * 4 + 2], w3 = cw[e * 4 + 3];
    float bias = cb[e];
    for (int t = tq; t < LQ; t += 16) {
      float s = bias + xs[t][le] * w3;
      if (t >= 1) s += xs[t - 1][le] * w2;
      if (t >= 2) s += xs[t - 2][le] * w1;
      if (t >= 3) s += xs[t - 3][le] * w0;
      us[t][le] = silu_f(s);
    }
  }
  __syncthreads();
  for (int i = threadIdx.x; i < 16 * LQ; i += 256) {
    int r = i / LQ, t = i % LQ;
    UT[(size_t)(e0 + r) * SLp + b * Lp + t] = us[t][r];
  }
  for (int i = threadIdx.x; i < LQ * 16; i += 256) {
    int tt = i >> 4, le = i & 15;
    UB[((size_t)(b * LQ + tt)) * ED + e0 + le] = f2bf(us[tt][le]);
  }
}

// ---------------- window scale+bias+silu -> UT2 + UB2 ----------------
__global__ __launch_bounds__(256) void k_win(
    const float* __restrict__ xin, const float* __restrict__ w2,
    const float* __restrict__ b2, float* __restrict__ UT,
    unsigned short* __restrict__ UB, int Lp, int SLp)
{
  __shared__ float us[49][17];
  int eb = blockIdx.x;   // 0..95
  int s  = blockIdx.y;   // 0..63
  int q = s >> 4, b = s & 15;
  int e0 = eb * 16;
  for (int i = threadIdx.x; i < 49 * 16; i += 256) {
    int j = i >> 4, le = i & 15;
    int hh = j / 7 + 7 * (q >> 1);
    int ww = j % 7 + 7 * (q & 1);
    int tok = hh * 14 + ww;
    int e = e0 + le;
    float x = xin[((size_t)(b * LQ + tok)) * ED + e];
    us[j][le] = silu_f(x * w2[e] + b2[e]);
  }
  __syncthreads();
  for (int i = threadIdx.x; i < 16 * 49; i += 256) {
    int r = i / 49, j = i % 49;
    UT[(size_t)(e0 + r) * SLp + s * Lp + j] = us[j][r];
  }
  for (int i = threadIdx.x; i < 49 * 16; i += 256) {
    int j = i >> 4, le = i & 15;
    UB[((size_t)(s * 49 + j)) * ED + e0 + le] = f2bf(us[j][le]);
  }
}

// ---------------- delta = softplus(dbc[:, :48] @ dt_w^T + dt_b) -> DT [e][s*Lp+t] ----------------
__global__ __launch_bounds__(256) void k_delta(
    const float* __restrict__ dbc, const float* __restrict__ dtw,
    const float* __restrict__ dtb, float* __restrict__ DT,
    int L, int Lp, int SLp)
{
  __shared__ float sd[16][DTR];
  int tbase = blockIdx.y * 16;
  int e = blockIdx.x * 256 + threadIdx.x;
  for (int i = threadIdx.x; i < 16 * DTR; i += 256)
    sd[i / DTR][i % DTR] = dbc[(size_t)(tbase + i / DTR) * 80 + (i % DTR)];
  __syncthreads();
  float w[DTR];
#pragma unroll
  for (int k = 0; k < DTR; ++k) w[k] = dtw[e * DTR + k];
  float bias = dtb[e];
  for (int tt = 0; tt < 16; ++tt) {
    float s = bias;
#pragma unroll
    for (int k = 0; k < DTR; ++k) s += sd[tt][k] * w[k];
    float dv = (s > 20.f) ? s : log1pf(__expf(s));
    int tok = tbase + tt;
    int sq = tok / L, t = tok - sq * L;
    DT[(size_t)e * SLp + sq * Lp + t] = dv;
  }
}

// ---------------- repack B,C columns of dbc into BT/CT [s*16+n][Lp+t] ----------------
__global__ void k_bc(const float* __restrict__ dbc, float* __restrict__ BT,
                     float* __restrict__ CT, int L, int Lp, int ntok) {
  int i = blockIdx.x * 256 + threadIdx.x;
  if (i >= ntok * 32) return;
  int tok = i >> 5, c = i & 31;
  int s = tok / L, t = tok - s * L;
  float v = dbc[(size_t)tok * 80 + 48 + c];
  if (c < 16) BT[(size_t)(s * 16 + c) * Lp + t] = v;
  else        CT[(size_t)(s * 16 + (c - 16)) * Lp + t] = v;
}

// ---------------- SSM scan: 16 lanes = 16 states per (s,e); writes Y[ti][e] ----------------
__global__ __launch_bounds__(256) void k_scan(
    const float* __restrict__ UT, const float* __restrict__ DT,
    const float* __restrict__ BT, const float* __restrict__ CT,
    const float* __restrict__ alog, float* __restrict__ Y,
    int L, int Lp, int SLp)
{
  int g = blockIdx.x * 16 + (threadIdx.x >> 4);
  int n = threadIdx.x & 15;
  int e = g % ED;
  int s = g / ED;
  float A = -__expf(alog[e * NS + n]);
  const float* dp = DT + (size_t)e * SLp + s * Lp;
  const float* up = UT + (size_t)e * SLp + s * Lp;
  const float* bp = BT + (size_t)(s * 16 + n) * Lp;
  const float* cp = CT + (size_t)(s * 16 + n) * Lp;
  float* yp = Y + (size_t)s * L * ED + e;
  float h = 0.f;
  for (int tb = 0; tb < L; tb += 4) {
    f32x4 d4 = *(const f32x4*)(dp + tb);
    f32x4 u4 = *(const f32x4*)(up + tb);
    f32x4 b4 = *(const f32x4*)(bp + tb);
    f32x4 c4 = *(const f32x4*)(cp + tb);
#pragma unroll
    for (int k = 0; k < 4; ++k) {
      if (tb + k < L) {
        float d = d4[k];
        h = __expf(d * A) * h + d * u4[k] * b4[k];
        float y = c4[k] * h;
        y += __shfl_xor(y, 8);
        y += __shfl_xor(y, 4);
        y += __shfl_xor(y, 2);
        y += __shfl_xor(y, 1);
        if (n == 0) yp[(tb + k) * ED] = y;
      }
    }
  }
}

// ---------------- combine 3 branch outputs + ct1 + *silu(z) -> bf16 PREB ----------------
__global__ void k_combine(const float* __restrict__ Y0, const float* __restrict__ Y1,
                          const float* __restrict__ Y2, const float* __restrict__ ZS,
                          unsigned short* __restrict__ PREB)
{
  int i = blockIdx.x * 256 + threadIdx.x;   // over NTOK * 384
  int tok = i / 384, e4 = (i - tok * 384) * 4;
  int b = tok / LQ, p = tok - b * LQ;

  int t0 = (p == 0) ? 196 : p - 1;
  f32x4 v0 = *(const f32x4*)(Y0 + ((size_t)(b * LQ + t0)) * ED + e4);

  int t1;
  if (p == 0) t1 = 196;
  else { int pp = p - 1; t1 = (pp % 14) * 14 + pp / 14; }
  f32x4 v1 = *(const f32x4*)(Y1 + ((size_t)(b * LQ + t1)) * ED + e4);

  f32x4 v2;
  if (p == 196) {
    v2 = *(const f32x4*)(Y1 + ((size_t)(b * LQ + 196)) * ED + e4);
  } else {
    int hh = p / 14, ww = p - hh * 14;
    int q = ((hh >= 7) ? 2 : 0) + ((ww >= 7) ? 1 : 0);
    int j = (hh % 7) * 7 + (ww % 7);
    v2 = *(const f32x4*)(Y2 + ((size_t)((q * 16 + b) * 49 + j)) * ED + e4);
  }
  f32x4 z = *(const f32x4*)(ZS + (size_t)tok * ED + e4);
  s16x4 r;
#pragma unroll
  for (int k = 0; k < 4; ++k) r[k] = (short)f2bf((v0[k] + v1[k] + v2[k]) * z[k]);
  *(s16x4*)(PREB + (size_t)tok * ED + e4) = r;
}

extern "C" void kernel_launch(void* const* d_in, const int* in_sizes, int n_in,
                              void* d_out, int out_size, void* d_ws, size_t ws_size,
                              hipStream_t stream)
{
  const float* x    = (const float*)d_in[0];
  const float* Win  = (const float*)d_in[1];
  const float* c0w  = (const float*)d_in[2];
  const float* c0b  = (const float*)d_in[3];
  const float* c1w  = (const float*)d_in[4];
  const float* c1b  = (const float*)d_in[5];
  const float* c2w  = (const float*)d_in[6];
  const float* c2b  = (const float*)d_in[7];
  const float* xp0  = (const float*)d_in[8];
  const float* xp1  = (const float*)d_in[9];
  const float* xp2  = (const float*)d_in[10];
  const float* dtw  = (const float*)d_in[11];
  const float* dtb  = (const float*)d_in[12];
  const float* alog = (const float*)d_in[13];
  const float* Wout = (const float*)d_in[15];
  float* out = (float*)d_out;

  // layout constants
  const int Lp0 = 200, SLp0 = 16 * 200;    // branches 0,1
  const int Lp2 = 52,  SLp2 = 64 * 52;     // branch 2
  const size_t UTSZ = (size_t)ED * (64 * 52);  // 5.11M floats, >= ED*16*200

  char* base = (char*)d_ws;
  size_t off = 0;
  auto alloc = [&](size_t bytes) -> char* {
    char* r = base + off;
    off = (off + bytes + 255) & ~(size_t)255;
    return r;
  };

  float* ZS   = (float*)alloc((size_t)NTOK * ED * 4);
  float* Y0   = (float*)alloc((size_t)NTOK * ED * 4);   // WINB aliased at start
  float* Y1   = (float*)alloc((size_t)NTOK * ED * 4);   // XB aliased at start
  float* XIN  = (float*)alloc((size_t)NTOK * ED * 4);   // Y2 aliased (used after XIN dead)
  float* UT   = (float*)alloc(UTSZ * 4);
  float* DT   = (float*)alloc(UTSZ * 4);
  unsigned short* UB   = (unsigned short*)alloc((size_t)NTOK * ED * 2);
  unsigned short* PREB = (unsigned short*)alloc((size_t)NTOK * ED * 2);
  unsigned short* WOUTB= (unsigned short*)alloc((size_t)DM * ED * 2);
  float* DBC  = (float*)alloc((size_t)NTOK * 80 * 4);
  float* BT   = (float*)alloc((size_t)64 * 16 * 52 * 4);
  float* CT   = (float*)alloc((size_t)64 * 16 * 52 * 4);
  unsigned short* XPB0 = (unsigned short*)alloc((size_t)80 * ED * 2);
  unsigned short* XPB1 = (unsigned short*)alloc((size_t)80 * ED * 2);
  unsigned short* XPB2 = (unsigned short*)alloc((size_t)80 * ED * 2);

  unsigned short* WINB = (unsigned short*)Y0;   // dead after gemm1; Y0 written later
  unsigned short* XB   = (unsigned short*)Y1;   // dead after gemm1; Y1 written later
  float* Y2 = XIN;                              // XIN dead after k_win; Y2 written later

  auto cvt = [&](const float* s, unsigned short* d, int n) {
    k_f2bf<<<(n + 255) / 256, 256, 0, stream>>>(s, d, n);
  };
  cvt(x, XB, NTOK * DM);
  cvt(Win, WINB, 2 * ED * DM);
  cvt(xp0, XPB0, 80 * ED);
  cvt(xp1, XPB1, 80 * ED);
  cvt(xp2, XPB2, 80 * ED);
  cvt(Wout, WOUTB, DM * ED);

  // xz = x @ W_in^T  -> XIN (first ED cols), ZS = silu(z)
  k_gemm<<<dim3(25, 24), 256, 0, stream>>>(XB, WINB, XIN, ZS, NTOK, 2 * ED, DM, 1);

  // ---- branch 0 ----
  k_conv<<<dim3(96, 16), 256, 0, stream>>>(XIN, c0w, c0b, UT, UB, 0, Lp0, SLp0);
  hipMemsetAsync(DBC, 0, (size_t)NTOK * 80 * 4, stream);
  k_dbc<<<788, 256, 0, stream>>>(UB, XPB0, DBC, NTOK);
  k_delta<<<dim3(6, 197), 256, 0, stream>>>(DBC, dtw, dtb, DT, LQ, Lp0, SLp0);
  k_bc<<<394, 256, 0, stream>>>(DBC, BT, CT, LQ, Lp0, NTOK);
  k_scan<<<1536, 256, 0, stream>>>(UT, DT, BT, CT, alog, Y0, LQ, Lp0, SLp0);

  // ---- branch 1 ----
  k_conv<<<dim3(96, 16), 256, 0, stream>>>(XIN, c1w, c1b, UT, UB, 1, Lp0, SLp0);
  hipMemsetAsync(DBC, 0, (size_t)NTOK * 80 * 4, stream);
  k_dbc<<<788, 256, 0, stream>>>(UB, XPB1, DBC, NTOK);
  k_delta<<<dim3(6, 197), 256, 0, stream>>>(DBC, dtw, dtb, DT, LQ, Lp0, SLp0);
  k_bc<<<394, 256, 0, stream>>>(DBC, BT, CT, LQ, Lp0, NTOK);
  k_scan<<<1536, 256, 0, stream>>>(UT, DT, BT, CT, alog, Y1, LQ, Lp0, SLp0);

  // ---- branch 2 (windows) ----
  k_win<<<dim3(96, 64), 256, 0, stream>>>(XIN, c2w, c2b, UT, UB, Lp2, SLp2);
  hipMemsetAsync(DBC, 0, (size_t)NWTOK * 80 * 4, stream);
  k_dbc<<<784, 256, 0, stream>>>(UB, XPB2, DBC, NWTOK);
  k_delta<<<dim3(6, 196), 256, 0, stream>>>(DBC, dtw, dtb, DT, 49, Lp2, SLp2);
  k_bc<<<392, 256, 0, stream>>>(DBC, BT, CT, 49, Lp2, NWTOK);
  k_scan<<<6144, 256, 0, stream>>>(UT, DT, BT, CT, alog, Y2, 49, Lp2, SLp2);

  // ---- combine + output GEMM ----
  k_combine<<<4728, 256, 0, stream>>>(Y0, Y1, Y2, ZS, PREB);
  k_gemm<<<dim3(25, 6), 256, 0, stream>>>(PREB, WOUTB, out, nullptr, NTOK, DM, ED, 0);
}

// Round 3
// 343.659 us; speedup vs baseline: 2.5959x; 1.8312x over previous
//
#include <hip/hip_runtime.h>
#include <hip/hip_bf16.h>
#include <math.h>

#define DM 768
#define ED 1536
#define NS 16
#define DTR 48
#define BATCH 16
#define LQ 197
#define NTOK (BATCH*LQ)      // 3152
#define NWTOK (64*49)        // 3136
#define TTOK (2*NTOK+NWTOK)  // 9440
#define TPAD 9456
#define MPAD 3200

typedef __attribute__((ext_vector_type(8))) short short8;
typedef __attribute__((ext_vector_type(4))) float f32x4;
typedef __attribute__((ext_vector_type(4))) short s16x4;

__device__ __forceinline__ unsigned short f2bf(float f) {
  unsigned int u = __float_as_uint(f);
  unsigned int r = (u + 0x7FFFu + ((u >> 16) & 1u)) >> 16;
  return (unsigned short)r;
}
__device__ __forceinline__ float bf2f(unsigned short u) {
  return __uint_as_float(((unsigned int)u) << 16);
}
__device__ __forceinline__ float silu_f(float x) {
  return x / (1.f + __expf(-x));
}

// ---------------- batched f32 -> bf16 convert of all weights/inputs ----------------
__global__ void k_cvtall(const float* __restrict__ x, const float* __restrict__ Win,
                         const float* __restrict__ xp0, const float* __restrict__ xp1,
                         const float* __restrict__ xp2, const float* __restrict__ Wout,
                         unsigned short* __restrict__ XB, unsigned short* __restrict__ WINB,
                         unsigned short* __restrict__ XPB, unsigned short* __restrict__ WOUTB)
{
  int i = blockIdx.x * 256 + threadIdx.x;
  const int n0 = NTOK * DM;
  const int n1 = n0 + 2 * ED * DM;
  const int n2 = n1 + 80 * ED;
  const int n3 = n2 + 80 * ED;
  const int n4 = n3 + 80 * ED;
  const int n5 = n4 + DM * ED;
  if (i < n0) XB[i] = f2bf(x[i]);
  else if (i < n1) WINB[i - n0] = f2bf(Win[i - n0]);
  else if (i < n2) XPB[i - n1] = f2bf(xp0[i - n1]);
  else if (i < n3) XPB[(i - n2) + 80 * ED] = f2bf(xp1[i - n2]);
  else if (i < n4) XPB[(i - n3) + 160 * ED] = f2bf(xp2[i - n3]);
  else if (i < n5) WOUTB[i - n4] = f2bf(Wout[i - n4]);
}

// ---------------- LDS-staged bf16 MFMA GEMM: C[M][N] = A[M][K] * B[N][K]^T ----------------
// 128x128 tile, BK=64, global_load_lds width 16, 2-barrier structure (m97).
// mode 0: plain fp32 store (ldc = N); mode 1: split epilogue (xin / silu(z)).
__global__ __launch_bounds__(256) void k_gemm_lds(
    const unsigned short* __restrict__ A, const unsigned short* __restrict__ B,
    float* __restrict__ C, float* __restrict__ C2,
    int M, int N, int K, int mode)
{
  __shared__ unsigned short As[128 * 64];
  __shared__ unsigned short Bs[128 * 64];
  int tid = threadIdx.x;
  int wave = tid >> 6, lane = tid & 63;
  int m0 = blockIdx.x * 128, n0 = blockIdx.y * 128;
  int wm = (wave >> 1) * 64, wn = (wave & 1) * 64;
  int lr = lane & 15, lk = lane >> 4;

  f32x4 acc[4][4];
#pragma unroll
  for (int i = 0; i < 4; ++i)
#pragma unroll
    for (int j = 0; j < 4; ++j) acc[i][j] = (f32x4){0.f, 0.f, 0.f, 0.f};

  const unsigned short* Ab = A + (size_t)m0 * K;
  const unsigned short* Bb = B + (size_t)n0 * K;

  for (int kk = 0; kk < K; kk += 64) {
    __syncthreads();
#pragma unroll
    for (int j = 0; j < 4; ++j) {
      int c = j * 256 + wave * 64 + lane;     // chunk index 0..1023 (16B chunks)
      int row = c >> 3, kc = c & 7;
      __builtin_amdgcn_global_load_lds(
        (const __attribute__((address_space(1))) unsigned int*)(Ab + (size_t)row * K + kk + kc * 8),
        (__attribute__((address_space(3))) unsigned int*)(As + (size_t)(j * 256 + wave * 64) * 8),
        16, 0, 0);
      __builtin_amdgcn_global_load_lds(
        (const __attribute__((address_space(1))) unsigned int*)(Bb + (size_t)row * K + kk + kc * 8),
        (__attribute__((address_space(3))) unsigned int*)(Bs + (size_t)(j * 256 + wave * 64) * 8),
        16, 0, 0);
    }
    __syncthreads();
#pragma unroll
    for (int ks = 0; ks < 2; ++ks) {
      short8 av[4], bv[4];
#pragma unroll
      for (int i = 0; i < 4; ++i) {
        av[i] = *(const short8*)(As + (wm + i * 16 + lr) * 64 + ks * 32 + lk * 8);
        bv[i] = *(const short8*)(Bs + (wn + i * 16 + lr) * 64 + ks * 32 + lk * 8);
      }
#pragma unroll
      for (int i = 0; i < 4; ++i)
#pragma unroll
        for (int jj = 0; jj < 4; ++jj)
          acc[i][jj] = __builtin_amdgcn_mfma_f32_16x16x32_bf16(av[i], bv[jj], acc[i][jj], 0, 0, 0);
    }
  }

  int cn = lane & 15, rb = (lane >> 4) * 4;
#pragma unroll
  for (int i = 0; i < 4; ++i)
#pragma unroll
    for (int jj = 0; jj < 4; ++jj)
#pragma unroll
      for (int r = 0; r < 4; ++r) {
        int row = m0 + wm + i * 16 + rb + r;
        int col = n0 + wn + jj * 16 + cn;
        if (row < M && col < N) {
          float v = acc[i][jj][r];
          if (mode == 1) {
            if (col < ED) C[(size_t)row * ED + col] = v;
            else          C2[(size_t)row * ED + (col - ED)] = silu_f(v);
          } else {
            C[(size_t)row * N + col] = v;
          }
        }
      }
}

// ---------------- causal depthwise conv (k=4) + bias + silu -> UB bf16 [tok][e] ----------------
// blockIdx.z = branch (0: identity perm, 1: 14x14-transpose perm)
__global__ __launch_bounds__(256) void k_conv(
    const float* __restrict__ xin,
    const float* __restrict__ cw0, const float* __restrict__ cb0,
    const float* __restrict__ cw1, const float* __restrict__ cb1,
    unsigned short* __restrict__ UB)
{
  int t = blockIdx.x, b = blockIdx.y, pz = blockIdx.z;
  const float* cw = pz ? cw1 : cw0;
  const float* cb = pz ? cb1 : cb0;
  int src[4];
#pragma unroll
  for (int k = 0; k < 4; ++k) {
    int tt = t - 3 + k;
    if (tt < 0) src[k] = -1;
    else if (pz == 0) src[k] = tt;
    else src[k] = (tt < 196) ? ((tt % 14) * 14 + tt / 14) : 196;
  }
  size_t obase = ((size_t)(pz * NTOK + b * LQ + t)) * ED;
  for (int e = threadIdx.x; e < ED; e += 256) {
    float s = cb[e];
#pragma unroll
    for (int k = 0; k < 4; ++k)
      if (src[k] >= 0) s += xin[((size_t)(b * LQ + src[k])) * ED + e] * cw[e * 4 + k];
    UB[obase + e] = f2bf(silu_f(s));
  }
}

// ---------------- window scale+bias+silu -> UB rows 6304.. ----------------
__global__ __launch_bounds__(256) void k_win(
    const float* __restrict__ xin, const float* __restrict__ w2,
    const float* __restrict__ b2, unsigned short* __restrict__ UB)
{
  int j = blockIdx.x;  // 0..48
  int s = blockIdx.y;  // 0..63  (= q*16+b)
  int q = s >> 4, b = s & 15;
  int hh = j / 7 + 7 * (q >> 1);
  int ww = j % 7 + 7 * (q & 1);
  int tok = hh * 14 + ww;
  size_t ibase = ((size_t)(b * LQ + tok)) * ED;
  size_t obase = ((size_t)(2 * NTOK + s * 49 + j)) * ED;
  for (int e = threadIdx.x; e < ED; e += 256)
    UB[obase + e] = f2bf(silu_f(xin[ibase + e] * w2[e] + b2[e]));
}

// ---------------- dbc GEMM: DBC[tok][80] = UB[tok][1536] @ XPB(branch)[80][1536]^T ----------------
// block = one 16-token tile; 4 waves = 4 k-splits (384 each); LDS reduce; no atomics.
__global__ __launch_bounds__(256) void k_dbc(
    const unsigned short* __restrict__ A, const unsigned short* __restrict__ XPB,
    float* __restrict__ C)
{
  __shared__ float red[4][16][80];
  int tid = threadIdx.x;
  int wave = tid >> 6, lane = tid & 63;
  int m0 = blockIdx.x * 16;
  int branch = (m0 >= 2 * NTOK) ? 2 : (m0 >= NTOK ? 1 : 0);
  const unsigned short* B = XPB + (size_t)branch * 80 * ED;
  int lr = lane & 15;
  int kof = wave * 384 + (lane >> 4) * 8;

  f32x4 acc[5];
#pragma unroll
  for (int j = 0; j < 5; ++j) acc[j] = (f32x4){0.f, 0.f, 0.f, 0.f};

  const unsigned short* Ap = A + (size_t)(m0 + lr) * ED + kof;
  const unsigned short* Bp = B + (size_t)lr * ED + kof;
#pragma unroll
  for (int kk = 0; kk < 384; kk += 32) {
    short8 av = *(const short8*)(Ap + kk);
#pragma unroll
    for (int j = 0; j < 5; ++j) {
      short8 bv = *(const short8*)(Bp + (size_t)j * 16 * ED + kk);
      acc[j] = __builtin_amdgcn_mfma_f32_16x16x32_bf16(av, bv, acc[j], 0, 0, 0);
    }
  }
  int cn = lane & 15, rb = (lane >> 4) * 4;
#pragma unroll
  for (int j = 0; j < 5; ++j)
#pragma unroll
    for (int r = 0; r < 4; ++r)
      red[wave][rb + r][j * 16 + cn] = acc[j][r];
  __syncthreads();
  for (int i = tid; i < 16 * 80; i += 256) {
    int r = i / 80, c = i % 80;
    C[(size_t)(m0 + r) * 80 + c] = red[0][r][c] + red[1][r][c] + red[2][r][c] + red[3][r][c];
  }
}

// ---------------- delta = softplus(dbc[:, :48] @ dt_w^T + dt_b) -> DELTA [tok][e] ----------------
__global__ __launch_bounds__(256) void k_delta(
    const float* __restrict__ dbc, const float* __restrict__ dtw,
    const float* __restrict__ dtb, float* __restrict__ DELTA)
{
  __shared__ float sd[16][DTR];
  int tbase = blockIdx.y * 16;
  int e = blockIdx.x * 256 + threadIdx.x;
  for (int i = threadIdx.x; i < 16 * DTR; i += 256)
    sd[i / DTR][i % DTR] = dbc[(size_t)(tbase + i / DTR) * 80 + (i % DTR)];
  __syncthreads();
  float w[DTR];
#pragma unroll
  for (int k = 0; k < DTR; ++k) w[k] = dtw[e * DTR + k];
  float bias = dtb[e];
  for (int tt = 0; tt < 16; ++tt) {
    float s = bias;
#pragma unroll
    for (int k = 0; k < DTR; ++k) s += sd[tt][k] * w[k];
    float dv = (s > 20.f) ? s : log1pf(__expf(s));
    DELTA[(size_t)(tbase + tt) * ED + e] = dv;
  }
}

// ---------------- SSM scan: 4 lanes x 4 states per (seq,e) group, all branches batched ----------------
__global__ __launch_bounds__(256) void k_scan(
    const unsigned short* __restrict__ UB, const float* __restrict__ DELTA,
    const float* __restrict__ DBC, const float* __restrict__ alog,
    float* __restrict__ Y0, float* __restrict__ Y1, float* __restrict__ Y2)
{
  int g = blockIdx.x * 64 + (threadIdx.x >> 2);
  int lq = threadIdx.x & 3;
  int seq = g / ED;          // 0..95
  int e = g - seq * ED;
  int n0 = lq * 4;

  float A0 = -__expf(alog[e * NS + n0 + 0]);
  float A1 = -__expf(alog[e * NS + n0 + 1]);
  float A2 = -__expf(alog[e * NS + n0 + 2]);
  float A3 = -__expf(alog[e * NS + n0 + 3]);

  int L, tokbase, yrow;
  float* Y;
  if (seq < 16)      { L = LQ; tokbase = seq * LQ;                 Y = Y0; yrow = seq * LQ; }
  else if (seq < 32) { L = LQ; tokbase = NTOK + (seq - 16) * LQ;   Y = Y1; yrow = (seq - 16) * LQ; }
  else               { L = 49; tokbase = 2 * NTOK + (seq - 32) * 49; Y = Y2; yrow = (seq - 32) * 49; }

  float h0 = 0.f, h1 = 0.f, h2 = 0.f, h3 = 0.f;
  for (int tb = 0; tb < L; tb += 4) {
    float u[4], d[4];
    f32x4 Bv[4], Cv[4];
#pragma unroll
    for (int k = 0; k < 4; ++k) {
      int tok = tokbase + tb + k;
      u[k] = bf2f(UB[(size_t)tok * ED + e]);
      d[k] = DELTA[(size_t)tok * ED + e];
      Bv[k] = *(const f32x4*)(DBC + (size_t)tok * 80 + DTR + n0);
      Cv[k] = *(const f32x4*)(DBC + (size_t)tok * 80 + DTR + NS + n0);
    }
#pragma unroll
    for (int k = 0; k < 4; ++k) {
      float du = d[k] * u[k];
      h0 = __expf(d[k] * A0) * h0 + du * Bv[k][0];
      h1 = __expf(d[k] * A1) * h1 + du * Bv[k][1];
      h2 = __expf(d[k] * A2) * h2 + du * Bv[k][2];
      h3 = __expf(d[k] * A3) * h3 + du * Bv[k][3];
      float y = Cv[k][0] * h0 + Cv[k][1] * h1 + Cv[k][2] * h2 + Cv[k][3] * h3;
      y += __shfl_xor(y, 1);
      y += __shfl_xor(y, 2);
      if (lq == 0 && tb + k < L) Y[(size_t)(yrow + tb + k) * ED + e] = y;
    }
  }
}

// ---------------- combine 3 branch outputs + ct1 + *silu(z) -> bf16 PREB ----------------
__global__ void k_combine(const float* __restrict__ Y0, const float* __restrict__ Y1,
                          const float* __restrict__ Y2, const float* __restrict__ ZS,
                          unsigned short* __restrict__ PREB)
{
  int i = blockIdx.x * 256 + threadIdx.x;   // over NTOK * 384
  int tok = i / 384, e4 = (i - tok * 384) * 4;
  int b = tok / LQ, p = tok - b * LQ;

  int t0 = (p == 0) ? 196 : p - 1;
  f32x4 v0 = *(const f32x4*)(Y0 + ((size_t)(b * LQ + t0)) * ED + e4);

  int t1;
  if (p == 0) t1 = 196;
  else { int pp = p - 1; t1 = (pp % 14) * 14 + pp / 14; }
  f32x4 v1 = *(const f32x4*)(Y1 + ((size_t)(b * LQ + t1)) * ED + e4);

  f32x4 v2;
  if (p == 196) {
    v2 = *(const f32x4*)(Y1 + ((size_t)(b * LQ + 196)) * ED + e4);
  } else {
    int hh = p / 14, ww = p - hh * 14;
    int q = ((hh >= 7) ? 2 : 0) + ((ww >= 7) ? 1 : 0);
    int j = (hh % 7) * 7 + (ww % 7);
    v2 = *(const f32x4*)(Y2 + ((size_t)((q * 16 + b) * 49 + j)) * ED + e4);
  }
  f32x4 z = *(const f32x4*)(ZS + (size_t)tok * ED + e4);
  s16x4 r;
#pragma unroll
  for (int k = 0; k < 4; ++k) r[k] = (short)f2bf((v0[k] + v1[k] + v2[k]) * z[k]);
  *(s16x4*)(PREB + (size_t)tok * ED + e4) = r;
}

extern "C" void kernel_launch(void* const* d_in, const int* in_sizes, int n_in,
                              void* d_out, int out_size, void* d_ws, size_t ws_size,
                              hipStream_t stream)
{
  const float* x    = (const float*)d_in[0];
  const float* Win  = (const float*)d_in[1];
  const float* c0w  = (const float*)d_in[2];
  const float* c0b  = (const float*)d_in[3];
  const float* c1w  = (const float*)d_in[4];
  const float* c1b  = (const float*)d_in[5];
  const float* c2w  = (const float*)d_in[6];
  const float* c2b  = (const float*)d_in[7];
  const float* xp0  = (const float*)d_in[8];
  const float* xp1  = (const float*)d_in[9];
  const float* xp2  = (const float*)d_in[10];
  const float* dtw  = (const float*)d_in[11];
  const float* dtb  = (const float*)d_in[12];
  const float* alog = (const float*)d_in[13];
  const float* Wout = (const float*)d_in[15];
  float* out = (float*)d_out;

  char* base = (char*)d_ws;
  size_t off = 0;
  auto alloc = [&](size_t bytes) -> char* {
    char* r = base + off;
    off = (off + bytes + 255) & ~(size_t)255;
    return r;
  };

  float* ZS    = (float*)alloc((size_t)NTOK * ED * 4);
  float* Y0    = (float*)alloc((size_t)NTOK * ED * 4);
  float* Y1    = (float*)alloc((size_t)NTOK * ED * 4);
  float* XIN   = (float*)alloc((size_t)NTOK * ED * 4);   // Y2 aliases after XIN is dead
  unsigned short* UB    = (unsigned short*)alloc((size_t)TPAD * ED * 2);
  float* DELTA = (float*)alloc((size_t)TPAD * ED * 4);
  float* DBC   = (float*)alloc((size_t)TPAD * 80 * 4);
  unsigned short* PREB  = (unsigned short*)alloc((size_t)MPAD * ED * 2);
  unsigned short* WOUTB = (unsigned short*)alloc((size_t)DM * ED * 2);
  unsigned short* XPB   = (unsigned short*)alloc((size_t)3 * 80 * ED * 2);

  // aliases: XB + WINB live inside Y0 until gemm1 done; Y2 = XIN (dead after conv/win).
  unsigned short* XB   = (unsigned short*)Y0;                                 // MPAD x DM
  unsigned short* WINB = (unsigned short*)((char*)Y0 + (size_t)MPAD * DM * 2); // 3072 x DM
  float* Y2 = XIN;

  // convert all fp32 operands to bf16 in one launch
  {
    int ntot = NTOK * DM + 2 * ED * DM + 3 * 80 * ED + DM * ED;
    k_cvtall<<<(ntot + 255) / 256, 256, 0, stream>>>(x, Win, xp0, xp1, xp2, Wout,
                                                     XB, WINB, XPB, WOUTB);
  }

  // xz = x @ W_in^T  -> XIN (first ED cols), ZS = silu(z)
  k_gemm_lds<<<dim3(25, 24), 256, 0, stream>>>(XB, WINB, XIN, ZS, NTOK, 2 * ED, DM, 1);

  hipMemsetAsync(DBC, 0, (size_t)TPAD * 80 * 4, stream);  // covers scan-tail padding rows

  // u for all three branches -> UB [9440][1536] bf16
  k_conv<<<dim3(LQ, BATCH, 2), 256, 0, stream>>>(XIN, c0w, c0b, c1w, c1b, UB);
  k_win<<<dim3(49, 64), 256, 0, stream>>>(XIN, c2w, c2b, UB);

  // dbc for all branches (per-token xproj selection)
  k_dbc<<<TTOK / 16, 256, 0, stream>>>(UB, XPB, DBC);

  // delta for all branches
  k_delta<<<dim3(6, TTOK / 16), 256, 0, stream>>>(DBC, dtw, dtb, DELTA);

  // batched scan over 96 sequences x 1536 channels
  k_scan<<<2304, 256, 0, stream>>>(UB, DELTA, DBC, alog, Y0, Y1, Y2);

  // combine + output GEMM
  k_combine<<<(NTOK * 384 + 255) / 256, 256, 0, stream>>>(Y0, Y1, Y2, ZS, PREB);
  k_gemm_lds<<<dim3(25, 6), 256, 0, stream>>>(PREB, WOUTB, out, nullptr, NTOK, DM, ED, 0);
}